// Round 1
// baseline (132.719 us; speedup 1.0000x reference)
//
#include <hip/hip_runtime.h>

#define B_   16
#define NK_  256
#define NQ_  256
#define DK_  256
#define H_   128
#define DV_  256

// 2*log2(e): features prescaled so exp2(kfc+qfc) = e^{2x}
#define C2X 2.8853900817779268f
// log2(e) for softmax exp
#define L2E 1.4426950408889634f

typedef float f4 __attribute__((ext_vector_type(4)));

__device__ __forceinline__ float exp2_fast(float x) { return __builtin_amdgcn_exp2f(x); }
__device__ __forceinline__ float rcp_fast(float x)  { return __builtin_amdgcn_rcpf(x); }

// ---------------------------------------------------------------------------
// Kernel A: projections, prescaled by C2X.
//   blocks 0..255   : kfc[b][k][h]  = C2X * (key  @ Wk)   (row-major)
//   blocks 256..511 : qfcT[b][h][q] = C2X * (query @ Wq)  (TRANSPOSED store)
// Each block: 16 flat rows x 128 cols. 256 threads.
// ---------------------------------------------------------------------------
__global__ __launch_bounds__(256) void proj_kernel(
    const float* __restrict__ key, const float* __restrict__ query,
    const float* __restrict__ Wk,  const float* __restrict__ Wq,
    float* __restrict__ kfc, float* __restrict__ qfcT)
{
    __shared__ alignas(16) float A_s[16 * 256];   // 16 KB input-row tile

    const int blk = blockIdx.x;
    const int tid = threadIdx.x;
    const bool isQ = blk >= 256;
    const int rb = (blk & 255) * 16;              // flat row base (b*256 + row)

    const float* __restrict__ A = isQ ? query : key;
    const float* __restrict__ W = isQ ? Wq : Wk;

    // stage 16x256 input rows (coalesced float4)
    {
        const f4* src = (const f4*)(A + (size_t)rb * DK_);
        f4* dst = (f4*)A_s;
#pragma unroll
        for (int j = 0; j < 4; ++j) dst[tid + 256 * j] = src[tid + 256 * j];
    }
    __syncthreads();

    const int c  = tid & 127;                     // output column (h)
    const int rg = (tid >> 7) * 8;                // row group: 8 rows each

    float acc[8];
#pragma unroll
    for (int i = 0; i < 8; ++i) acc[i] = 0.f;

    for (int kk = 0; kk < DK_; kk += 4) {
        const float w0 = W[(size_t)(kk + 0) * H_ + c];
        const float w1 = W[(size_t)(kk + 1) * H_ + c];
        const float w2 = W[(size_t)(kk + 2) * H_ + c];
        const float w3 = W[(size_t)(kk + 3) * H_ + c];
#pragma unroll
        for (int i = 0; i < 8; ++i) {
            f4 a = *(const f4*)(A_s + (rg + i) * 256 + kk);  // wave-uniform broadcast
            acc[i] = fmaf(a[0], w0, acc[i]);
            acc[i] = fmaf(a[1], w1, acc[i]);
            acc[i] = fmaf(a[2], w2, acc[i]);
            acc[i] = fmaf(a[3], w3, acc[i]);
        }
    }

    if (!isQ) {
        const int r = rb + rg;
#pragma unroll
        for (int i = 0; i < 8; ++i)
            kfc[(size_t)(r + i) * H_ + c] = C2X * acc[i];
    } else {
        const int b  = rb >> 8;
        const int q0 = (rb & 255) + rg;
        float* dstq = qfcT + ((size_t)b * H_ + c) * NQ_ + q0;
#pragma unroll
        for (int j = 0; j < 2; ++j) {
            f4 v;
            v[0] = C2X * acc[4 * j + 0];
            v[1] = C2X * acc[4 * j + 1];
            v[2] = C2X * acc[4 * j + 2];
            v[3] = C2X * acc[4 * j + 3];
            *(f4*)(dstq + 4 * j) = v;
        }
    }
}

// ---------------------------------------------------------------------------
// Kernel B: fused scores + masked softmax + PV.
// 1024 blocks: 4 k-rows each. Decode rotates b per quarter so each CU/XCD
// gets mixed batches (load balance across random valid_lens + L2 locality).
// Phase-1 q-range is contiguous PER WAVE so the valid_len skip is wave-granular.
// ---------------------------------------------------------------------------
__global__ __launch_bounds__(256) void attn_kernel(
    const float* __restrict__ kfc, const float* __restrict__ qfcT,
    const float* __restrict__ value, const int* __restrict__ vlens,
    const float* __restrict__ wv, float* __restrict__ out)
{
    __shared__ alignas(16) float kf_s[4 * 132];   // k-rows, stride 132 (conflict-free)
    __shared__ alignas(16) float wv2_s[128];      // 2*wv
    __shared__ alignas(16) float sc_s[4 * 260];   // scores/attn, stride 260

    const int x   = blockIdx.x;
    const int qu  = x >> 8;                       // 0..3
    const int xi  = x & 255;
    const int b   = (xi + (qu << 2)) & 15;
    const int kt  = (xi >> 4) + (qu << 4);        // 0..63
    const int k0  = kt << 2;
    const int tid = threadIdx.x;
    const int valid = vlens[b];

    // stage kf tile (4 x 128) and 2*wv
    if (tid < 128) {
        const int k = tid >> 5, h4 = tid & 31;
        f4 v = ((const f4*)(kfc + ((size_t)(b * NK_ + k0 + k)) * H_))[h4];
        *(f4*)(kf_s + k * 132 + (h4 << 2)) = v;
    }
    if (tid < 32) {
        f4 w = ((const f4*)wv)[tid];
        ((f4*)wv2_s)[tid] = 2.f * w;
    }
    __syncthreads();

    // sum(wv) = 0.5 * sum(wv2) — cheap broadcast reads, every thread
    float sumwv = 0.f;
#pragma unroll
    for (int i = 0; i < 32; ++i) {
        f4 w = ((const f4*)wv2_s)[i];
        sumwv += (w[0] + w[1]) + (w[2] + w[3]);
    }
    sumwv *= 0.5f;

    // ---- Phase 1: scores.  thread = (k-row g, 4 q's).  wave covers q in
    // [64w, 64w+63] so masked-q skip drops whole waves.
    {
        const int g  = tid & 3;
        const int q4 = (tid >> 2) << 2;
        if (q4 < valid) {
            const float* qbase = qfcT + (size_t)b * (H_ * NQ_) + q4;
            const float* kb = kf_s + g * 132;
            float acc0 = 0.f, acc1 = 0.f, acc2 = 0.f, acc3 = 0.f;
            for (int h = 0; h < H_; h += 4) {
                f4 w4 = *(const f4*)(wv2_s + h);
                f4 kA = *(const f4*)(kb + h);
                f4 qq[4];
                qq[0] = *(const f4*)(qbase + (size_t)(h + 0) * NQ_);
                qq[1] = *(const f4*)(qbase + (size_t)(h + 1) * NQ_);
                qq[2] = *(const f4*)(qbase + (size_t)(h + 2) * NQ_);
                qq[3] = *(const f4*)(qbase + (size_t)(h + 3) * NQ_);
#pragma unroll
                for (int j = 0; j < 4; ++j) {
                    const float kj = kA[j];
                    const float wj = w4[j];
                    const f4 qv = qq[j];
                    // wv*tanh(x) = wv - wv2 / (e^{2x}+1); inputs prescaled
                    float r;
                    r = rcp_fast(exp2_fast(kj + qv[0]) + 1.f); acc0 = fmaf(wj, r, acc0);
                    r = rcp_fast(exp2_fast(kj + qv[1]) + 1.f); acc1 = fmaf(wj, r, acc1);
                    r = rcp_fast(exp2_fast(kj + qv[2]) + 1.f); acc2 = fmaf(wj, r, acc2);
                    r = rcp_fast(exp2_fast(kj + qv[3]) + 1.f); acc3 = fmaf(wj, r, acc3);
                }
            }
            f4 s;
            s[0] = sumwv - acc0; s[1] = sumwv - acc1;
            s[2] = sumwv - acc2; s[3] = sumwv - acc3;
            *(f4*)(sc_s + g * 260 + q4) = s;
        }
    }
    __syncthreads();

    // ---- Phase 2: masked softmax over q, one k-row per wave.
    {
        const int k   = tid >> 6;
        const int sub = tid & 63;
        const float* row = sc_s + k * 260;
        float ev[4];
        float m = -3.0e38f;
#pragma unroll
        for (int j = 0; j < 4; ++j) {
            const int q = sub + (j << 6);
            ev[j] = (q < valid) ? row[q] : -3.0e38f;
            m = fmaxf(m, ev[j]);
        }
#pragma unroll
        for (int off = 32; off >= 1; off >>= 1)
            m = fmaxf(m, __shfl_xor(m, off, 64));
        float ssum = 0.f;
#pragma unroll
        for (int j = 0; j < 4; ++j) {
            const int q = sub + (j << 6);
            const float e = (q < valid) ? exp2_fast(L2E * (ev[j] - m)) : 0.f;
            ev[j] = e;
            ssum += e;
        }
#pragma unroll
        for (int off = 32; off >= 1; off >>= 1)
            ssum += __shfl_xor(ssum, off, 64);
        const float inv = rcp_fast(ssum);
        float* roww = sc_s + k * 260;
#pragma unroll
        for (int j = 0; j < 4; ++j) {
            const int q = sub + (j << 6);
            if (q < valid) roww[q] = ev[j] * inv;
        }
    }
    __syncthreads();

    // ---- Phase 3: out[b][k0+g][d] = sum_{q<valid} attn * value[b][q][d]
    {
        const int g3 = tid >> 6;
        const int d4 = (tid & 63) << 2;
        const float* vb = value + (size_t)b * (NQ_ * DV_) + d4;
        const float* ap = sc_s + g3 * 260;
        f4 o = {0.f, 0.f, 0.f, 0.f};
#pragma unroll 4
        for (int q = 0; q < valid; ++q) {
            f4 v = *(const f4*)(vb + (size_t)q * DV_);
            o += ap[q] * v;
        }
        *(f4*)(out + ((size_t)(b * NK_ + k0 + g3)) * DV_ + d4) = o;
    }
}

// ---------------------------------------------------------------------------
extern "C" void kernel_launch(void* const* d_in, const int* in_sizes, int n_in,
                              void* d_out, int out_size, void* d_ws, size_t ws_size,
                              hipStream_t stream)
{
    const float* key   = (const float*)d_in[0];
    const float* query = (const float*)d_in[1];
    const float* value = (const float*)d_in[2];
    const int*   vlens = (const int*)  d_in[3];
    const float* Wk    = (const float*)d_in[4];
    const float* Wq    = (const float*)d_in[5];
    const float* wv    = (const float*)d_in[6];
    float* outp = (float*)d_out;

    float* kfc  = (float*)d_ws;                       // [B][NK][H]  2 MB
    float* qfcT = kfc + (size_t)B_ * NK_ * H_;        // [B][H][NQ]  2 MB

    hipLaunchKernelGGL(proj_kernel, dim3(512), dim3(256), 0, stream,
                       key, query, Wk, Wq, kfc, qfcT);
    hipLaunchKernelGGL(attn_kernel, dim3(1024), dim3(256), 0, stream,
                       kfc, qfcT, value, vlens, wv, outp);
}

// Round 2
// 118.255 us; speedup vs baseline: 1.1223x; 1.1223x over previous
//
#include <hip/hip_runtime.h>

#define B_   16
#define NK_  256
#define NQ_  256
#define DK_  256
#define H_   128
#define DV_  256

// 2*log2(e): features prescaled so exp2(kfc+qfc) = e^{2x}
#define C2X 2.8853900817779268f
// log2(e) for softmax exp
#define L2E 1.4426950408889634f

typedef float f4 __attribute__((ext_vector_type(4)));

__device__ __forceinline__ float exp2_fast(float x) { return __builtin_amdgcn_exp2f(x); }
__device__ __forceinline__ float rcp_fast(float x)  { return __builtin_amdgcn_rcpf(x); }

// ---------------------------------------------------------------------------
// Kernel A: projections, prescaled by C2X. 256 blocks x 256 threads.
//   blocks 0..127   : kfc[b][k][h]  = C2X * (key  @ Wk)   (row-major)
//   blocks 128..255 : qfcT[b][h][q] = C2X * (query @ Wq)  (TRANSPOSED)
// Block = 32 flat rows x 128 cols; thread = 4x4 register micro-tile.
// A-tile (32KB) + W-chunk (32KB) in LDS -> ~1 B LDS per fma, VALU-bound.
// ---------------------------------------------------------------------------
__global__ __launch_bounds__(256) void proj_kernel(
    const float* __restrict__ key, const float* __restrict__ query,
    const float* __restrict__ Wk,  const float* __restrict__ Wq,
    float* __restrict__ kfc, float* __restrict__ qfcT)
{
    __shared__ alignas(16) float A_s[32 * 256];   // 32 KB
    __shared__ alignas(16) float W_s[64 * 128];   // 32 KB

    const int blk = blockIdx.x;
    const int tid = threadIdx.x;
    const bool isQ = blk >= 128;
    const int rb = (blk & 127) * 32;              // flat row base (b*256 + row)

    const float* __restrict__ A = isQ ? query : key;
    const float* __restrict__ W = isQ ? Wq : Wk;

    // stage 32 x 256 input rows (coalesced float4, 8 per thread)
    {
        const f4* src = (const f4*)(A + (size_t)rb * DK_);
        f4* dst = (f4*)A_s;
#pragma unroll
        for (int j = 0; j < 8; ++j) dst[tid + 256 * j] = src[tid + 256 * j];
    }

    const int rg = (tid >> 5) * 4;                // row group: 4 rows
    const int c4 = (tid & 31) * 4;                // col base:  4 cols

    f4 acc[4];
#pragma unroll
    for (int r = 0; r < 4; ++r) acc[r] = (f4){0.f, 0.f, 0.f, 0.f};

    for (int kc = 0; kc < DK_; kc += 64) {
        __syncthreads();                          // prev chunk's reads done (and A_s staged)
        {
            const f4* wsrc = (const f4*)(W + (size_t)kc * H_);
            f4* wdst = (f4*)W_s;
#pragma unroll
            for (int j = 0; j < 8; ++j) wdst[tid + 256 * j] = wsrc[tid + 256 * j];
        }
        __syncthreads();
#pragma unroll 2
        for (int k = 0; k < 64; k += 4) {
            f4 w0 = *(const f4*)(W_s + (k + 0) * H_ + c4);
            f4 w1 = *(const f4*)(W_s + (k + 1) * H_ + c4);
            f4 w2 = *(const f4*)(W_s + (k + 2) * H_ + c4);
            f4 w3 = *(const f4*)(W_s + (k + 3) * H_ + c4);
#pragma unroll
            for (int r = 0; r < 4; ++r) {
                f4 a = *(const f4*)(A_s + (rg + r) * 256 + kc + k);
                acc[r] += a[0] * w0;
                acc[r] += a[1] * w1;
                acc[r] += a[2] * w2;
                acc[r] += a[3] * w3;
            }
        }
    }

    if (!isQ) {
        float* dst = kfc + (size_t)(rb + rg) * H_ + c4;
#pragma unroll
        for (int r = 0; r < 4; ++r)
            *(f4*)(dst + (size_t)r * H_) = C2X * acc[r];
    } else {
        const int b  = rb >> 8;
        const int q0 = (rb & 255) + rg;
#pragma unroll
        for (int cc = 0; cc < 4; ++cc) {
            f4 o;
            o[0] = C2X * acc[0][cc]; o[1] = C2X * acc[1][cc];
            o[2] = C2X * acc[2][cc]; o[3] = C2X * acc[3][cc];
            *(f4*)(qfcT + ((size_t)b * H_ + c4 + cc) * NQ_ + q0) = o;
        }
    }
}

// ---------------------------------------------------------------------------
// Kernel B: fused scores + masked softmax + PV.  1024 blocks x 256 threads,
// 4 k-rows per block, b rotated per dispatch round (XCD/load balance).
// Phase 1: wave->q-range assignment ROTATED per block so idle (masked) waves
//          spread across all 4 SIMDs instead of pinning SIMD 2/3.
// Phase 3: waves take q = rq (mod 4) interleaved; each thread accumulates ALL
//          4 k-rows (16 fma per value-f4) -> value read once per block (4x
//          less L2 traffic), cross-wave reduce through LDS at the end.
// ---------------------------------------------------------------------------
__global__ __launch_bounds__(256) void attn_kernel(
    const float* __restrict__ kfc, const float* __restrict__ qfcT,
    const float* __restrict__ value, const int* __restrict__ vlens,
    const float* __restrict__ wv, float* __restrict__ out)
{
    __shared__ alignas(16) float kf_s[4 * 132];    // k-features
    __shared__ alignas(16) float wv2_s[128];       // 2*wv
    __shared__ alignas(16) float sc_s[4 * 260];    // scores [k][q]
    __shared__ alignas(16) float at4_s[256 * 4];   // attn transposed [q][k]
    __shared__ alignas(16) float red_s[16 * 256];  // phase-3 partials [rq*4+k][d]

    const int x   = blockIdx.x;
    const int qu  = x >> 8;                        // dispatch round 0..3
    const int xi  = x & 255;
    const int b   = (xi + (qu << 2)) & 15;
    const int kt  = (xi >> 4) + (qu << 4);         // 0..63
    const int k0  = kt << 2;
    const int rot = ((xi >> 4) + qu) & 3;          // varies across co-resident blocks
    const int tid = threadIdx.x;
    const int valid = vlens[b];

    // stage kf tile (4 x 128) and 2*wv
    if (tid < 128) {
        const int k = tid >> 5, h4 = tid & 31;
        f4 v = ((const f4*)(kfc + ((size_t)(b * NK_ + k0 + k)) * H_))[h4];
        *(f4*)(kf_s + k * 132 + (h4 << 2)) = v;
    }
    if (tid < 32) {
        f4 w = ((const f4*)wv)[tid];
        ((f4*)wv2_s)[tid] = 2.f * w;
    }
    __syncthreads();

    // sum(wv): 32 global f4 loads (L1-broadcast), 4 independent add chains
    float sumwv;
    {
        f4 sw = {0.f, 0.f, 0.f, 0.f};
#pragma unroll
        for (int i = 0; i < 32; ++i) sw += ((const f4*)wv)[i];
        sumwv = (sw[0] + sw[1]) + (sw[2] + sw[3]);
    }

    // ---- Phase 1: scores.  thread = (k-row g, 4 q's); wave w covers q-range
    // 64*((w+rot)&3) so masked-out ranges rotate across SIMDs.
    {
        const int g     = tid & 3;
        const int range = ((tid >> 6) + rot) & 3;
        const int q4    = ((((tid >> 2) & 15)) << 2) + (range << 6);
        if (q4 < valid) {
            const float* qbase = qfcT + (size_t)b * (H_ * NQ_) + q4;
            const float* kb = kf_s + g * 132;
            float acc0 = 0.f, acc1 = 0.f, acc2 = 0.f, acc3 = 0.f;
            for (int h = 0; h < H_; h += 4) {
                f4 w4 = *(const f4*)(wv2_s + h);
                f4 kA = *(const f4*)(kb + h);
                f4 qq[4];
                qq[0] = *(const f4*)(qbase + (size_t)(h + 0) * NQ_);
                qq[1] = *(const f4*)(qbase + (size_t)(h + 1) * NQ_);
                qq[2] = *(const f4*)(qbase + (size_t)(h + 2) * NQ_);
                qq[3] = *(const f4*)(qbase + (size_t)(h + 3) * NQ_);
#pragma unroll
                for (int j = 0; j < 4; ++j) {
                    const float kj = kA[j];
                    const float wj = w4[j];
                    const f4 qv = qq[j];
                    // wv*tanh(x) = wv - wv2/(e^{2x}+1); inputs prescaled
                    float r;
                    r = rcp_fast(exp2_fast(kj + qv[0]) + 1.f); acc0 = fmaf(wj, r, acc0);
                    r = rcp_fast(exp2_fast(kj + qv[1]) + 1.f); acc1 = fmaf(wj, r, acc1);
                    r = rcp_fast(exp2_fast(kj + qv[2]) + 1.f); acc2 = fmaf(wj, r, acc2);
                    r = rcp_fast(exp2_fast(kj + qv[3]) + 1.f); acc3 = fmaf(wj, r, acc3);
                }
            }
            f4 s;
            s[0] = sumwv - acc0; s[1] = sumwv - acc1;
            s[2] = sumwv - acc2; s[3] = sumwv - acc3;
            *(f4*)(sc_s + g * 260 + q4) = s;
        }
    }
    __syncthreads();

    // ---- Phase 2: masked softmax over q, one k-row per wave; write attn
    // TRANSPOSED to at4_s[q][k] for phase 3 broadcast reads.
    {
        const int k   = tid >> 6;
        const int sub = tid & 63;
        const float* row = sc_s + k * 260;
        float ev[4];
        float m = -3.0e38f;
#pragma unroll
        for (int j = 0; j < 4; ++j) {
            const int q = sub + (j << 6);
            ev[j] = (q < valid) ? row[q] : -3.0e38f;
            m = fmaxf(m, ev[j]);
        }
#pragma unroll
        for (int off = 32; off >= 1; off >>= 1)
            m = fmaxf(m, __shfl_xor(m, off, 64));
        float ssum = 0.f;
#pragma unroll
        for (int j = 0; j < 4; ++j) {
            const int q = sub + (j << 6);
            const float e = (q < valid) ? exp2_fast(L2E * (ev[j] - m)) : 0.f;
            ev[j] = e;
            ssum += e;
        }
#pragma unroll
        for (int off = 32; off >= 1; off >>= 1)
            ssum += __shfl_xor(ssum, off, 64);
        const float inv = rcp_fast(ssum);
#pragma unroll
        for (int j = 0; j < 4; ++j) {
            const int q = sub + (j << 6);
            if (q < valid) at4_s[(q << 2) + k] = ev[j] * inv;
        }
    }
    __syncthreads();

    // ---- Phase 3: out[b][k0+k][d] = sum_q attn[q][k] * value[b][q][d]
    // wave rq takes q = rq (mod 4); thread holds all 4 k accumulators.
    {
        const int rq = tid >> 6;
        const int d4 = (tid & 63) << 2;
        const float* vb = value + (size_t)b * (NQ_ * DV_) + d4;
        f4 o0 = {0.f,0.f,0.f,0.f}, o1 = o0, o2 = o0, o3 = o0;
#pragma unroll 4
        for (int q = rq; q < valid; q += 4) {
            f4 v  = *(const f4*)(vb + (size_t)q * DV_);
            f4 a4 = *(const f4*)(at4_s + (q << 2));   // uniform broadcast
            o0 += a4[0] * v;
            o1 += a4[1] * v;
            o2 += a4[2] * v;
            o3 += a4[3] * v;
        }
        float* rs = red_s + (rq << 10) + d4;          // red_s[rq*4+k][256]
        *(f4*)(rs + 0)    = o0;
        *(f4*)(rs + 256)  = o1;
        *(f4*)(rs + 512)  = o2;
        *(f4*)(rs + 768)  = o3;
    }
    __syncthreads();

    // cross-wave reduce + store: thread = (k = tid>>6, d4)
    {
        const int k  = tid >> 6;
        const int d4 = (tid & 63) << 2;
        const float* rs = red_s + (k << 8) + d4;
        f4 o = *(const f4*)(rs) + *(const f4*)(rs + 1024)
             + *(const f4*)(rs + 2048) + *(const f4*)(rs + 3072);
        *(f4*)(out + ((size_t)(b * NK_ + k0 + k)) * DV_ + d4) = o;
    }
}

// ---------------------------------------------------------------------------
extern "C" void kernel_launch(void* const* d_in, const int* in_sizes, int n_in,
                              void* d_out, int out_size, void* d_ws, size_t ws_size,
                              hipStream_t stream)
{
    const float* key   = (const float*)d_in[0];
    const float* query = (const float*)d_in[1];
    const float* value = (const float*)d_in[2];
    const int*   vlens = (const int*)  d_in[3];
    const float* Wk    = (const float*)d_in[4];
    const float* Wq    = (const float*)d_in[5];
    const float* wv    = (const float*)d_in[6];
    float* outp = (float*)d_out;

    float* kfc  = (float*)d_ws;                       // [B][NK][H]  2 MB
    float* qfcT = kfc + (size_t)B_ * NK_ * H_;        // [B][H][NQ]  2 MB

    hipLaunchKernelGGL(proj_kernel, dim3(256), dim3(256), 0, stream,
                       key, query, Wk, Wq, kfc, qfcT);
    hipLaunchKernelGGL(attn_kernel, dim3(1024), dim3(256), 0, stream,
                       kfc, qfcT, value, vlens, wv, outp);
}

// Round 3
// 102.878 us; speedup vs baseline: 1.2901x; 1.1495x over previous
//
#include <hip/hip_runtime.h>

#define B_   16
#define NK_  256
#define NQ_  256
#define DK_  256
#define H_   128
#define DV_  256

// 2*log2(e): features prescaled so exp2(C2X*x) = e^{2x}
#define C2X 2.8853900817779268f
// log2(e) for softmax exp
#define L2E 1.4426950408889634f
#define MASKV -1.0e5f

typedef float f4 __attribute__((ext_vector_type(4)));

__device__ __forceinline__ float exp2_fast(float x) { return __builtin_amdgcn_exp2f(x); }
__device__ __forceinline__ float rcp_fast(float x)  { return __builtin_amdgcn_rcpf(x); }

// ---------------------------------------------------------------------------
// Kernel A: projections -> EXponentiated features.
//   blocks 0..127   : kfE[b][k][h]        = exp2(C2X * (key  @ Wk))
//   blocks 128..255 : qE4[b][h/4][q][4]   = exp2(C2X * (query @ Wq))  (h4-interleaved)
// Block = 32 flat rows x 128 cols; thread = 4x4 register micro-tile.
// ---------------------------------------------------------------------------
__global__ __launch_bounds__(256) void proj_kernel(
    const float* __restrict__ key, const float* __restrict__ query,
    const float* __restrict__ Wk,  const float* __restrict__ Wq,
    float* __restrict__ kfE, float* __restrict__ qE4)
{
    __shared__ alignas(16) float A_s[32 * 256];   // 32 KB
    __shared__ alignas(16) float W_s[64 * 128];   // 32 KB

    const int blk = blockIdx.x;
    const int tid = threadIdx.x;
    const bool isQ = blk >= 128;
    const int rb = (blk & 127) * 32;              // flat row base (b*256 + row)

    const float* __restrict__ A = isQ ? query : key;
    const float* __restrict__ W = isQ ? Wq : Wk;

    // stage 32 x 256 input rows (coalesced float4, 8 per thread)
    {
        const f4* src = (const f4*)(A + (size_t)rb * DK_);
        f4* dst = (f4*)A_s;
#pragma unroll
        for (int j = 0; j < 8; ++j) dst[tid + 256 * j] = src[tid + 256 * j];
    }

    const int rg = (tid >> 5) * 4;                // row group: 4 rows
    const int c4 = (tid & 31) * 4;                // col base:  4 cols

    f4 acc[4];
#pragma unroll
    for (int r = 0; r < 4; ++r) acc[r] = (f4){0.f, 0.f, 0.f, 0.f};

    for (int kc = 0; kc < DK_; kc += 64) {
        __syncthreads();                          // A_s staged / prev W reads done
        {
            const f4* wsrc = (const f4*)(W + (size_t)kc * H_);
            f4* wdst = (f4*)W_s;
#pragma unroll
            for (int j = 0; j < 8; ++j) wdst[tid + 256 * j] = wsrc[tid + 256 * j];
        }
        __syncthreads();
#pragma unroll 2
        for (int k = 0; k < 64; k += 4) {
            f4 w0 = *(const f4*)(W_s + (k + 0) * H_ + c4);
            f4 w1 = *(const f4*)(W_s + (k + 1) * H_ + c4);
            f4 w2 = *(const f4*)(W_s + (k + 2) * H_ + c4);
            f4 w3 = *(const f4*)(W_s + (k + 3) * H_ + c4);
#pragma unroll
            for (int r = 0; r < 4; ++r) {
                f4 a = *(const f4*)(A_s + (rg + r) * 256 + kc + k);
                acc[r] += a[0] * w0;
                acc[r] += a[1] * w1;
                acc[r] += a[2] * w2;
                acc[r] += a[3] * w3;
            }
        }
    }

    if (!isQ) {
        float* dst = kfE + (size_t)(rb + rg) * H_ + c4;
#pragma unroll
        for (int r = 0; r < 4; ++r) {
            f4 o;
#pragma unroll
            for (int cc = 0; cc < 4; ++cc) o[cc] = exp2_fast(C2X * acc[r][cc]);
            *(f4*)(dst + (size_t)r * H_) = o;
        }
    } else {
        const int b  = rb >> 8;
        const int q0 = (rb & 255) + rg;
        // qE4 f4-index: (b*32 + h4)*256 + q ; this thread's h4 = c4>>2
        f4* dst = (f4*)qE4 + ((size_t)(b * 32 + (c4 >> 2))) * NQ_ + q0;
#pragma unroll
        for (int r = 0; r < 4; ++r) {
            f4 o;
#pragma unroll
            for (int cc = 0; cc < 4; ++cc) o[cc] = exp2_fast(C2X * acc[r][cc]);
            dst[r] = o;
        }
    }
}

// ---------------------------------------------------------------------------
// Kernel B: fused scores + masked softmax + PV.  1024 blocks x 256 threads.
// Wave w owns k-row k0+w entirely: lane=q within 64-q chunks, chunk loop is
// wave-uniform (ceil(valid/64) chunks) -> perfect intra-block balance, no
// divergence waste, softmax fully in-wave (no barriers for phases 1-2).
// Per term: v_fma(ek,eq,1) + v_rcp + v_fmac  (E-features precomputed).
// Phase 3 shares value reads across the 4 k-rows via LDS (round-2 scheme).
// ---------------------------------------------------------------------------
__global__ __launch_bounds__(256) void attn_kernel(
    const float* __restrict__ kfE, const float* __restrict__ qE4,
    const float* __restrict__ value, const int* __restrict__ vlens,
    const float* __restrict__ wv, float* __restrict__ out)
{
    __shared__ alignas(16) float kf_s[4 * 132];    // Ek rows (pad stride 132)
    __shared__ alignas(16) float wv2_s[128];       // 2*wv
    __shared__ alignas(16) float at4_s[256 * 4];   // attn transposed [q][k]
    __shared__ alignas(16) float red_s[16 * 256];  // phase-3 partials

    const int x   = blockIdx.x;
    const int qu  = x >> 8;                        // dispatch round 0..3
    const int xi  = x & 255;
    const int b   = (xi + (qu << 2)) & 15;         // b rotated for balance
    const int kt  = (xi >> 4) + (qu << 4);         // 0..63
    const int k0  = kt << 2;
    const int tid = threadIdx.x;
    const int w   = tid >> 6;                      // wave = k-row
    const int lane = tid & 63;
    const int valid  = vlens[b];
    const int nchunk = (valid + 63) >> 6;          // 1..4

    // stage Ek tile (4 x 128) and 2*wv
    if (tid < 128) {
        const int k = tid >> 5, h4 = tid & 31;
        f4 v = ((const f4*)(kfE + ((size_t)(b * NK_ + k0 + k)) * H_))[h4];
        *(f4*)(kf_s + k * 132 + (h4 << 2)) = v;
    }
    if (tid < 32) {
        f4 wvv = ((const f4*)wv)[tid];
        ((f4*)wv2_s)[tid] = 2.f * wvv;
    }
    __syncthreads();

    // sum(wv): global f4 loads (L1 broadcast), 4 independent chains
    float sumwv;
    {
        f4 sw = {0.f, 0.f, 0.f, 0.f};
#pragma unroll
        for (int i = 0; i < 32; ++i) sw += ((const f4*)wv)[i];
        sumwv = (sw[0] + sw[1]) + (sw[2] + sw[3]);
    }

    // ---- Phase 1: scores for k-row (k0+w), q = 64j+lane, j < nchunk.
    float accA[4], accB[4];
#pragma unroll
    for (int j = 0; j < 4; ++j) { accA[j] = 0.f; accB[j] = 0.f; }

    {
        const f4* eq0 = (const f4*)qE4 + (size_t)b * (32 * NQ_) + lane;
        const float* kb = kf_s + w * 132;

        auto run = [&](int NC) {
            const f4* eqp = eq0;
#pragma unroll 4
            for (int h4 = 0; h4 < 32; ++h4) {
                f4 ek = *(const f4*)(kb + (h4 << 2));
                f4 w2 = *(const f4*)(wv2_s + (h4 << 2));
#pragma unroll
                for (int j = 0; j < 4; ++j) {
                    if (j >= NC) break;
                    f4 eq = eqp[j << 6];
                    float t0 = fmaf(ek[0], eq[0], 1.f);
                    float t1 = fmaf(ek[1], eq[1], 1.f);
                    float t2 = fmaf(ek[2], eq[2], 1.f);
                    float t3 = fmaf(ek[3], eq[3], 1.f);
                    accA[j] = fmaf(w2[0], rcp_fast(t0), accA[j]);
                    accB[j] = fmaf(w2[1], rcp_fast(t1), accB[j]);
                    accA[j] = fmaf(w2[2], rcp_fast(t2), accA[j]);
                    accB[j] = fmaf(w2[3], rcp_fast(t3), accB[j]);
                }
                eqp += NQ_;
            }
        };
        switch (nchunk) {
            case 1: run(1); break;
            case 2: run(2); break;
            case 3: run(3); break;
            default: run(4); break;
        }
    }

    // ---- Phase 2: softmax in-wave over this k-row's 256 q (4 chunk regs).
    {
        float s[4];
#pragma unroll
        for (int j = 0; j < 4; ++j) {
            const int q = (j << 6) + lane;
            s[j] = (j < nchunk && q < valid) ? (sumwv - (accA[j] + accB[j])) : MASKV;
        }
        float m = fmaxf(fmaxf(s[0], s[1]), fmaxf(s[2], s[3]));
#pragma unroll
        for (int off = 32; off >= 1; off >>= 1)
            m = fmaxf(m, __shfl_xor(m, off, 64));
        float ssum = 0.f;
#pragma unroll
        for (int j = 0; j < 4; ++j) {
            s[j] = exp2_fast(L2E * (s[j] - m));   // masked -> exp2(huge neg) = 0
            ssum += s[j];
        }
#pragma unroll
        for (int off = 32; off >= 1; off >>= 1)
            ssum += __shfl_xor(ssum, off, 64);
        const float inv = rcp_fast(ssum);
#pragma unroll
        for (int j = 0; j < 4; ++j)
            at4_s[(((j << 6) + lane) << 2) + w] = s[j] * inv;
    }
    __syncthreads();

    // ---- Phase 3: out[b][k0+k][d] = sum_q attn[q][k] * value[b][q][d]
    // wave rq takes q = rq (mod 4); thread holds all 4 k accumulators.
    {
        const int rq = tid >> 6;
        const int d4 = (tid & 63) << 2;
        const float* vb = value + (size_t)b * (NQ_ * DV_) + d4;
        f4 o0 = {0.f,0.f,0.f,0.f}, o1 = o0, o2 = o0, o3 = o0;
#pragma unroll 4
        for (int q = rq; q < valid; q += 4) {
            f4 v  = *(const f4*)(vb + (size_t)q * DV_);
            f4 a4 = *(const f4*)(at4_s + (q << 2));   // uniform broadcast
            o0 += a4[0] * v;
            o1 += a4[1] * v;
            o2 += a4[2] * v;
            o3 += a4[3] * v;
        }
        float* rs = red_s + (rq << 10) + d4;          // red_s[rq*4+k][256]
        *(f4*)(rs + 0)    = o0;
        *(f4*)(rs + 256)  = o1;
        *(f4*)(rs + 512)  = o2;
        *(f4*)(rs + 768)  = o3;
    }
    __syncthreads();

    // cross-wave reduce + store
    {
        const int k  = tid >> 6;
        const int d4 = (tid & 63) << 2;
        const float* rs = red_s + (k << 8) + d4;
        f4 o = *(const f4*)(rs) + *(const f4*)(rs + 1024)
             + *(const f4*)(rs + 2048) + *(const f4*)(rs + 3072);
        *(f4*)(out + ((size_t)(b * NK_ + k0 + k)) * DV_ + d4) = o;
    }
}

// ---------------------------------------------------------------------------
extern "C" void kernel_launch(void* const* d_in, const int* in_sizes, int n_in,
                              void* d_out, int out_size, void* d_ws, size_t ws_size,
                              hipStream_t stream)
{
    const float* key   = (const float*)d_in[0];
    const float* query = (const float*)d_in[1];
    const float* value = (const float*)d_in[2];
    const int*   vlens = (const int*)  d_in[3];
    const float* Wk    = (const float*)d_in[4];
    const float* Wq    = (const float*)d_in[5];
    const float* wv    = (const float*)d_in[6];
    float* outp = (float*)d_out;

    float* kfE = (float*)d_ws;                        // [B][NK][H]      2 MB
    float* qE4 = kfE + (size_t)B_ * NK_ * H_;         // [B][H/4][NQ][4] 2 MB

    hipLaunchKernelGGL(proj_kernel, dim3(256), dim3(256), 0, stream,
                       key, query, Wk, Wq, kfE, qE4);
    hipLaunchKernelGGL(attn_kernel, dim3(1024), dim3(256), 0, stream,
                       kfE, qE4, value, vlens, wv, outp);
}